// Round 3
// baseline (869.964 us; speedup 1.0000x reference)
//
#include <hip/hip_runtime.h>
#include <hip/hip_bf16.h>
#include <hip/hip_fp16.h>

#define DIMK 1024
#define SEQ  2048
#define BATCH 4
#define NTOK (BATCH*SEQ)                    // 8192
#define PROJ_ELEMS ((size_t)NTOK*DIMK)      // 8388608
#define LD 2048                             // leading dim (elements) of every GEMM operand

typedef unsigned short ushort_t;
typedef __attribute__((ext_vector_type(8))) short short8;   // 8 x bf16 (4 VGPRs)
typedef __attribute__((ext_vector_type(4))) float float4v;  // MFMA accumulator

__device__ __forceinline__ unsigned short f2bf(float f) {
    union { float f; unsigned int i; } x; x.f = f;
    unsigned int r = x.i + 0x7fffu + ((x.i >> 16) & 1u);    // RNE
    return (unsigned short)(r >> 16);
}

// global -> LDS direct copy, 16 B per lane. LDS dest is wave-uniform base;
// HW scatters lane i to base + i*16. Source address is PER-LANE.
__device__ __forceinline__ void gld_lds16(const void* g, void* l) {
    auto gp = reinterpret_cast<const __attribute__((address_space(1))) unsigned int*>(
        reinterpret_cast<uintptr_t>(g));
    auto lp = reinterpret_cast<__attribute__((address_space(3))) unsigned int*>(
        reinterpret_cast<uintptr_t>(l));
    __builtin_amdgcn_global_load_lds(gp, lp, 16, 0, 0);
}

// ---------------------------------------------------------------------------
// Shared MFMA core: C(128x128) += A(128xK) * B(128xK)^T, both row-major bf16
// with leading dim LD=2048. Block = 256 threads = 4 waves (2x2 of 64x64).
//
// LDS is staged in FRAGMENT ORDER: sub-chunk c holds the 16x32 tile for rows
// [c*16, c*16+16): lane l of the staging instruction sources global row
// c*16+(l&15), cols k0+(l>>4)*8, so it lands at LDS base+l*16 exactly where
// the MFMA fragment read wants it. Fragment reads are then ds_read_b128 at
// base + lane*16 -> contiguous 1024B per wave, zero bank conflicts.
// ---------------------------------------------------------------------------
__device__ __forceinline__ void gemm_core(
    const ushort_t* __restrict__ Arow,   // A + m0*LD
    const ushort_t* __restrict__ Brow,   // B + n0*LD
    int kbeg, int kend,
    ushort_t* Asm, ushort_t* Bsm,        // LDS, 128*32 bf16 each (8 sub-chunks of 512 elems)
    float4v acc[4][4], int wave, int lane)
{
    const int r0 = (wave * 2    ) * 16 + (lane & 15);   // staging source rows
    const int r1 = (wave * 2 + 1) * 16 + (lane & 15);
    const int kc = (lane >> 4) * 8;                     // staging source col offset
    const int cA = (wave >> 1) * 4;                     // this wave's A sub-chunk base
    const int cB = (wave & 1) * 4;                      // this wave's B sub-chunk base

    for (int k0 = kbeg; k0 < kend; k0 += 32) {
        gld_lds16(Arow + (size_t)r0 * LD + k0 + kc, Asm + (wave * 2    ) * 512);
        gld_lds16(Arow + (size_t)r1 * LD + k0 + kc, Asm + (wave * 2 + 1) * 512);
        gld_lds16(Brow + (size_t)r0 * LD + k0 + kc, Bsm + (wave * 2    ) * 512);
        gld_lds16(Brow + (size_t)r1 * LD + k0 + kc, Bsm + (wave * 2 + 1) * 512);
        __syncthreads();
        short8 af[4], bfr[4];
        #pragma unroll
        for (int i = 0; i < 4; ++i)
            af[i] = *(const short8*)(Asm + (cA + i) * 512 + lane * 8);
        #pragma unroll
        for (int j = 0; j < 4; ++j)
            bfr[j] = *(const short8*)(Bsm + (cB + j) * 512 + lane * 8);
        #pragma unroll
        for (int i = 0; i < 4; ++i)
            #pragma unroll
            for (int j = 0; j < 4; ++j)
                acc[i][j] = __builtin_amdgcn_mfma_f32_16x16x32_bf16(af[i], bfr[j], acc[i][j], 0, 0, 0);
        __syncthreads();
    }
}

// ---------------------------------------------------------------------------
// Projection GEMM: C[8192,2048] bf16 = Zcat[8192,2048] @ Wstack[2048,2048]^T
// grid (N/128=16, M/128=64)
// ---------------------------------------------------------------------------
__global__ __launch_bounds__(256)
void gemm_proj(const ushort_t* __restrict__ A, const ushort_t* __restrict__ B,
               ushort_t* __restrict__ C)
{
    __shared__ ushort_t Asm[128 * 32], Bsm[128 * 32];
    const int tid = threadIdx.x, wave = tid >> 6, lane = tid & 63;
    const int m0 = blockIdx.y * 128, n0 = blockIdx.x * 128;
    float4v acc[4][4] = {};
    gemm_core(A + (size_t)m0 * LD, B + (size_t)n0 * LD, 0, 2048, Asm, Bsm, acc, wave, lane);

    const int wm = (wave >> 1) * 64, wn = (wave & 1) * 64;
    const int col16 = lane & 15, quad = lane >> 4;
    #pragma unroll
    for (int i = 0; i < 4; ++i)
        #pragma unroll
        for (int j = 0; j < 4; ++j) {
            const int n = n0 + wn + j * 16 + col16;
            #pragma unroll
            for (int r = 0; r < 4; ++r) {
                const int m = m0 + wm + i * 16 + quad * 4 + r;
                C[(size_t)m * LD + n] = f2bf(acc[i][j][r]);
            }
        }
}

// ---------------------------------------------------------------------------
// Scores GEMM (causal tiles): S[b][s][t] fp16 = (Qcat@Kcat^T)*scale
// grid (16 t-tiles, 16 s-tiles, 4 batches); skip jt>it.
// ---------------------------------------------------------------------------
__global__ __launch_bounds__(256)
void gemm_scores(const ushort_t* __restrict__ Q, const ushort_t* __restrict__ K,
                 __half* __restrict__ S)
{
    const int jt = blockIdx.x, it = blockIdx.y, b = blockIdx.z;
    if (jt > it) return;
    __shared__ ushort_t Asm[128 * 32], Bsm[128 * 32];
    const int tid = threadIdx.x, wave = tid >> 6, lane = tid & 63;
    const size_t boff = (size_t)b * SEQ * LD;
    float4v acc[4][4] = {};
    gemm_core(Q + boff + (size_t)it * 128 * LD, K + boff + (size_t)jt * 128 * LD,
              0, 2048, Asm, Bsm, acc, wave, lane);

    const int wm = (wave >> 1) * 64, wn = (wave & 1) * 64;
    const int col16 = lane & 15, quad = lane >> 4;
    const float scale = 0.03125f;  // 1024^-0.5
    __half* Sb = S + (size_t)b * SEQ * SEQ;
    #pragma unroll
    for (int i = 0; i < 4; ++i)
        #pragma unroll
        for (int j = 0; j < 4; ++j) {
            const int t = jt * 128 + wn + j * 16 + col16;
            #pragma unroll
            for (int r = 0; r < 4; ++r) {
                const int s = it * 128 + wm + i * 16 + quad * 4 + r;
                Sb[(size_t)s * SEQ + t] = __float2half(acc[i][j][r] * scale);
            }
        }
}

// ---------------------------------------------------------------------------
// PV GEMM: out[{r,i}][b][s][d] fp32 = P[b] @ VTstack[b]^T, K extent causal.
// grid (16 n-tiles, 16 s-tiles, 4 batches). n<1024 -> real, else imag.
// ---------------------------------------------------------------------------
__global__ __launch_bounds__(256)
void gemm_pv(const ushort_t* __restrict__ P, const ushort_t* __restrict__ VT,
             float* __restrict__ out)
{
    const int nt = blockIdx.x, mt = blockIdx.y, b = blockIdx.z;
    __shared__ ushort_t Asm[128 * 32], Bsm[128 * 32];
    const int tid = threadIdx.x, wave = tid >> 6, lane = tid & 63;
    const int kend = (mt + 1) * 128;
    float4v acc[4][4] = {};
    gemm_core(P + (size_t)b * SEQ * SEQ + (size_t)mt * 128 * LD,
              VT + (size_t)b * LD * LD + (size_t)nt * 128 * LD,
              0, kend, Asm, Bsm, acc, wave, lane);

    const int wm = (wave >> 1) * 64, wn = (wave & 1) * 64;
    const int col16 = lane & 15, quad = lane >> 4;
    #pragma unroll
    for (int i = 0; i < 4; ++i)
        #pragma unroll
        for (int j = 0; j < 4; ++j) {
            const int n = nt * 128 + wn + j * 16 + col16;
            float* dst = out + ((n < 1024) ? 0 : PROJ_ELEMS);
            const int d = n & 1023;
            #pragma unroll
            for (int r = 0; r < 4; ++r) {
                const int s = mt * 128 + wm + i * 16 + quad * 4 + r;
                dst[((size_t)b * SEQ + s) * DIMK + d] = acc[i][j][r];
            }
        }
}

// ---------------------------------------------------------------------------
// Input converts
// ---------------------------------------------------------------------------
__global__ __launch_bounds__(256)
void zcat_kernel(const float* __restrict__ zr, const float* __restrict__ zi,
                 ushort_t* __restrict__ zcat)
{
    const size_t e = ((size_t)blockIdx.x * 256 + threadIdx.x) * 8;
    const size_t tok = e >> 11;
    const int c = (int)(e & 2047);
    const float* src = (c < 1024) ? (zr + tok * 1024 + c) : (zi + tok * 1024 + (c - 1024));
    float4 a = *(const float4*)src;
    float4 b = *(const float4*)(src + 4);
    ushort_t* d = zcat + e;
    d[0]=f2bf(a.x); d[1]=f2bf(a.y); d[2]=f2bf(a.z); d[3]=f2bf(a.w);
    d[4]=f2bf(b.x); d[5]=f2bf(b.y); d[6]=f2bf(b.z); d[7]=f2bf(b.w);
}

// Wstack[n][c]: n<1024: [wr[n] | -wi[n]] ; n>=1024: [wi[n-1024] | wr[n-1024]]
__global__ __launch_bounds__(256)
void wstack_kernel(const float* __restrict__ wr, const float* __restrict__ wi,
                   ushort_t* __restrict__ ws)
{
    const size_t e = ((size_t)blockIdx.x * 256 + threadIdx.x) * 8;
    const int n = (int)(e >> 11), c = (int)(e & 2047);
    const int n1 = n & 1023, c1 = c & 1023;
    const float* src;
    float sgn = 1.f;
    if (n < 1024) {
        if (c < 1024) src = wr + (size_t)n1 * 1024 + c1;
        else        { src = wi + (size_t)n1 * 1024 + c1; sgn = -1.f; }
    } else {
        src = ((c < 1024) ? wi : wr) + (size_t)n1 * 1024 + c1;
    }
    float4 a = *(const float4*)src;
    float4 b = *(const float4*)(src + 4);
    ushort_t* d = ws + e;
    d[0]=f2bf(sgn*a.x); d[1]=f2bf(sgn*a.y); d[2]=f2bf(sgn*a.z); d[3]=f2bf(sgn*a.w);
    d[4]=f2bf(sgn*b.x); d[5]=f2bf(sgn*b.y); d[6]=f2bf(sgn*b.z); d[7]=f2bf(sgn*b.w);
}

// ---------------------------------------------------------------------------
// V transpose per batch: VT[b][c][t] = Vcat[b*SEQ + t][c], 64x64 LDS tiles.
// grid (32 t-tiles, 32 c-tiles, 4 batches)
// ---------------------------------------------------------------------------
__global__ __launch_bounds__(256)
void transpose_v(const ushort_t* __restrict__ vcat, ushort_t* __restrict__ vt)
{
    __shared__ ushort_t tile[64][65];
    const int b = blockIdx.z;
    const int t0 = blockIdx.x * 64, c0 = blockIdx.y * 64;
    const int tid = threadIdx.x;
    const int r = tid >> 4, c4 = (tid & 15) * 4;
    const ushort_t* src = vcat + ((size_t)(b * SEQ + t0)) * LD + c0;
    #pragma unroll
    for (int p = 0; p < 4; ++p) {
        const int row = p * 16 + r;
        ushort4 v = *(const ushort4*)(src + (size_t)row * LD + c4);
        tile[row][c4+0]=v.x; tile[row][c4+1]=v.y; tile[row][c4+2]=v.z; tile[row][c4+3]=v.w;
    }
    __syncthreads();
    ushort_t* dst = vt + ((size_t)b * LD + c0) * LD + t0;
    #pragma unroll
    for (int p = 0; p < 4; ++p) {
        const int crow = p * 16 + r;
        ushort4 v;
        v.x = tile[c4+0][crow]; v.y = tile[c4+1][crow];
        v.z = tile[c4+2][crow]; v.w = tile[c4+3][crow];
        *(ushort4*)(dst + (size_t)crow * LD + c4) = v;
    }
}

// ---------------------------------------------------------------------------
// Causal softmax: read fp16 scores row [0,s], write bf16 P in place,
// zero-padded to a 128 multiple so PV consumes whole K tiles.
// ---------------------------------------------------------------------------
__global__ __launch_bounds__(256)
void softmax_kernel(__half* __restrict__ sc)
{
    const int row = blockIdx.x;          // b*SEQ + s
    const int s = row & (SEQ - 1);
    __half* x = sc + (size_t)row * SEQ;
    ushort_t* xo = (ushort_t*)x;
    const int n = s + 1;
    const int tid = threadIdx.x, wave = tid >> 6, lane = tid & 63;
    __shared__ float redm[4], reds[4];

    float m = -1e30f;
    for (int i = tid; i < n; i += 256) m = fmaxf(m, __half2float(x[i]));
    #pragma unroll
    for (int off = 32; off > 0; off >>= 1) m = fmaxf(m, __shfl_down(m, off, 64));
    if (lane == 0) redm[wave] = m;
    __syncthreads();
    if (tid == 0) redm[0] = fmaxf(fmaxf(redm[0], redm[1]), fmaxf(redm[2], redm[3]));
    __syncthreads();
    m = redm[0];

    float l = 0.f;
    for (int i = tid; i < n; i += 256) l += __expf(__half2float(x[i]) - m);
    #pragma unroll
    for (int off = 32; off > 0; off >>= 1) l += __shfl_down(l, off, 64);
    if (lane == 0) reds[wave] = l;
    __syncthreads();
    if (tid == 0) reds[0] = reds[0] + reds[1] + reds[2] + reds[3];
    __syncthreads();
    const float inv = 1.0f / reds[0];

    const int npad = min(SEQ, ((s >> 7) + 1) << 7);
    for (int i = tid; i < npad; i += 256) {
        float v = (i < n) ? __expf(__half2float(x[i]) - m) * inv : 0.f;
        xo[i] = f2bf(v);
    }
}

// ---------------------------------------------------------------------------
extern "C" void kernel_launch(void* const* d_in, const int* in_sizes, int n_in,
                              void* d_out, int out_size, void* d_ws, size_t ws_size,
                              hipStream_t stream)
{
    const float* z_real = (const float*)d_in[0];
    const float* z_imag = (const float*)d_in[1];
    const float* wq_r   = (const float*)d_in[2];
    const float* wq_i   = (const float*)d_in[3];
    const float* wk_r   = (const float*)d_in[4];
    const float* wk_i   = (const float*)d_in[5];
    const float* wv_r   = (const float*)d_in[6];
    const float* wv_i   = (const float*)d_in[7];
    // d_in[8]: causal tril mask, handled analytically.

    // Workspace layout (bytes), lifetimes are disjoint by stream order:
    //   [0,          33554432)  Zcat bf16     -> reused as VT bf16
    //   [33554432,   58720256)  Wstack q/k/v bf16 (3 x 8 MiB)
    //   [58720256,   92274688)  Qcat bf16
    //   [92274688,  125829120)  Kcat bf16
    //   [125829120, 159383552)  Vcat bf16     -> reused as scores fp16 / P bf16
    uint8_t* ws = (uint8_t*)d_ws;
    ushort_t* zcat = (ushort_t*)(ws + 0);
    ushort_t* wsq  = (ushort_t*)(ws + 33554432);
    ushort_t* wsk  = (ushort_t*)(ws + 33554432 + 8388608);
    ushort_t* wsv  = (ushort_t*)(ws + 33554432 + 16777216);
    ushort_t* qcat = (ushort_t*)(ws + 58720256);
    ushort_t* kcat = (ushort_t*)(ws + 92274688);
    ushort_t* vcat = (ushort_t*)(ws + 125829120);
    ushort_t* vt   = (ushort_t*)(ws + 0);
    __half*   sc   = (__half*)(ws + 125829120);
    float*    outp = (float*)d_out;

    zcat_kernel<<<dim3(8192), dim3(256), 0, stream>>>(z_real, z_imag, zcat);
    wstack_kernel<<<dim3(2048), dim3(256), 0, stream>>>(wq_r, wq_i, wsq);
    wstack_kernel<<<dim3(2048), dim3(256), 0, stream>>>(wk_r, wk_i, wsk);
    wstack_kernel<<<dim3(2048), dim3(256), 0, stream>>>(wv_r, wv_i, wsv);

    gemm_proj<<<dim3(16, 64), dim3(256), 0, stream>>>(zcat, wsq, qcat);
    gemm_proj<<<dim3(16, 64), dim3(256), 0, stream>>>(zcat, wsk, kcat);
    gemm_proj<<<dim3(16, 64), dim3(256), 0, stream>>>(zcat, wsv, vcat);

    transpose_v<<<dim3(32, 32, 4), dim3(256), 0, stream>>>(vcat, vt);
    gemm_scores<<<dim3(16, 16, 4), dim3(256), 0, stream>>>(qcat, kcat, sc);
    softmax_kernel<<<dim3(NTOK), dim3(256), 0, stream>>>(sc);
    gemm_pv<<<dim3(16, 16, 4), dim3(256), 0, stream>>>((ushort_t*)sc, vt, outp);
}

// Round 4
// 631.001 us; speedup vs baseline: 1.3787x; 1.3787x over previous
//
#include <hip/hip_runtime.h>
#include <hip/hip_bf16.h>
#include <hip/hip_fp16.h>

#define DIMK 1024
#define SEQ  2048
#define BATCH 4
#define NTOK (BATCH*SEQ)                    // 8192
#define PROJ_ELEMS ((size_t)NTOK*DIMK)      // 8388608
#define LD 2048                             // leading dim (elements) of every GEMM operand

typedef unsigned short ushort_t;
typedef __attribute__((ext_vector_type(8))) short short8;   // 8 x bf16 (4 VGPRs)
typedef __attribute__((ext_vector_type(4))) float float4v;  // MFMA accumulator

__device__ __forceinline__ unsigned short f2bf(float f) {
    union { float f; unsigned int i; } x; x.f = f;
    unsigned int r = x.i + 0x7fffu + ((x.i >> 16) & 1u);    // RNE
    return (unsigned short)(r >> 16);
}

// global -> LDS direct copy, 16 B per lane. LDS dest is wave-uniform base;
// HW scatters lane i to base + i*16. Source address is PER-LANE but MUST keep
// consecutive-lane groups within aligned lines for coalescing (R3 lesson).
__device__ __forceinline__ void gld_lds16(const void* g, void* l) {
    auto gp = reinterpret_cast<const __attribute__((address_space(1))) unsigned int*>(
        reinterpret_cast<uintptr_t>(g));
    auto lp = reinterpret_cast<__attribute__((address_space(3))) unsigned int*>(
        reinterpret_cast<uintptr_t>(l));
    __builtin_amdgcn_global_load_lds(gp, lp, 16, 0, 0);
}

// ---------------------------------------------------------------------------
// Shared MFMA core: C(128x128) += A(128xK) * B(128xK)^T, both row-major bf16
// with leading dim LD=2048. Block = 256 threads = 4 waves (2x2 of 64x64).
//
// LDS swizzle: each 16-row sub-chunk (512 elems) stores row g's 16B chunk c
// at slot x = (c + g/2) & 3. Staging lane l (slot row g=l>>2, x=l&3) therefore
// sources global chunk ((l&3) - (l>>3)) & 3 of row g — a permutation WITHIN
// the same 64B line, so lanes 4g..4g+3 still cover one aligned 64B segment
// (coalescing preserved). Fragment read: lane l reads row r=l&15 at slot
// ((quad + r/2) & 3)*16B -> every 8 consecutive lanes hit all 32 banks once
// (zero conflicts).
// ---------------------------------------------------------------------------
__device__ __forceinline__ void gemm_core(
    const ushort_t* __restrict__ Arow,   // A + m0*LD
    const ushort_t* __restrict__ Brow,   // B + n0*LD
    int kbeg, int kend,
    ushort_t* Asm, ushort_t* Bsm,        // LDS, 128*32 bf16 each (8 sub-chunks of 512 elems)
    float4v acc[4][4], int wave, int lane)
{
    const int g  = lane >> 2;                         // staging row within sub-chunk
    const int sx = lane & 3;                          // staging slot within 64B line
    const int scol = (((sx - (g >> 1)) & 3)) * 8;     // swizzled source chunk (elements)
    const int sc0 = wave * 2, sc1 = wave * 2 + 1;     // this wave's staging sub-chunks
    const int r16  = lane & 15;                       // fragment row
    const int quad = lane >> 4;                       // fragment k-chunk
    const int swz  = ((quad + (r16 >> 1)) & 3) * 8;   // swizzled read chunk (elements)
    const int cA = (wave >> 1) * 4;                   // wave's A sub-chunk base
    const int cB = (wave & 1) * 4;                    // wave's B sub-chunk base

    for (int k0 = kbeg; k0 < kend; k0 += 32) {
        gld_lds16(Arow + (size_t)(sc0 * 16 + g) * LD + k0 + scol, Asm + sc0 * 512);
        gld_lds16(Arow + (size_t)(sc1 * 16 + g) * LD + k0 + scol, Asm + sc1 * 512);
        gld_lds16(Brow + (size_t)(sc0 * 16 + g) * LD + k0 + scol, Bsm + sc0 * 512);
        gld_lds16(Brow + (size_t)(sc1 * 16 + g) * LD + k0 + scol, Bsm + sc1 * 512);
        __syncthreads();
        short8 af[4], bfr[4];
        #pragma unroll
        for (int i = 0; i < 4; ++i)
            af[i] = *(const short8*)(Asm + (cA + i) * 512 + r16 * 32 + swz);
        #pragma unroll
        for (int j = 0; j < 4; ++j)
            bfr[j] = *(const short8*)(Bsm + (cB + j) * 512 + r16 * 32 + swz);
        #pragma unroll
        for (int i = 0; i < 4; ++i)
            #pragma unroll
            for (int j = 0; j < 4; ++j)
                acc[i][j] = __builtin_amdgcn_mfma_f32_16x16x32_bf16(af[i], bfr[j], acc[i][j], 0, 0, 0);
        __syncthreads();
    }
}

// ---------------------------------------------------------------------------
// Projection GEMM: C[8192,2048] bf16 = Zcat[8192,2048] @ Wstack[2048,2048]^T
// grid (N/128=16, M/128=64)
// ---------------------------------------------------------------------------
__global__ __launch_bounds__(256)
void gemm_proj(const ushort_t* __restrict__ A, const ushort_t* __restrict__ B,
               ushort_t* __restrict__ C)
{
    __shared__ ushort_t Asm[128 * 32], Bsm[128 * 32];
    const int tid = threadIdx.x, wave = tid >> 6, lane = tid & 63;
    const int m0 = blockIdx.y * 128, n0 = blockIdx.x * 128;
    float4v acc[4][4] = {};
    gemm_core(A + (size_t)m0 * LD, B + (size_t)n0 * LD, 0, 2048, Asm, Bsm, acc, wave, lane);

    const int wm = (wave >> 1) * 64, wn = (wave & 1) * 64;
    const int col16 = lane & 15, quad = lane >> 4;
    #pragma unroll
    for (int i = 0; i < 4; ++i)
        #pragma unroll
        for (int j = 0; j < 4; ++j) {
            const int n = n0 + wn + j * 16 + col16;
            #pragma unroll
            for (int r = 0; r < 4; ++r) {
                const int m = m0 + wm + i * 16 + quad * 4 + r;
                C[(size_t)m * LD + n] = f2bf(acc[i][j][r]);
            }
        }
}

// ---------------------------------------------------------------------------
// Scores GEMM (causal tiles): S[b][s][t] fp16 = (Qcat@Kcat^T)*scale
// grid (16 t-tiles, 16 s-tiles, 4 batches); skip jt>it.
// ---------------------------------------------------------------------------
__global__ __launch_bounds__(256)
void gemm_scores(const ushort_t* __restrict__ Q, const ushort_t* __restrict__ K,
                 __half* __restrict__ S)
{
    const int jt = blockIdx.x, it = blockIdx.y, b = blockIdx.z;
    if (jt > it) return;
    __shared__ ushort_t Asm[128 * 32], Bsm[128 * 32];
    const int tid = threadIdx.x, wave = tid >> 6, lane = tid & 63;
    const size_t boff = (size_t)b * SEQ * LD;
    float4v acc[4][4] = {};
    gemm_core(Q + boff + (size_t)it * 128 * LD, K + boff + (size_t)jt * 128 * LD,
              0, 2048, Asm, Bsm, acc, wave, lane);

    const int wm = (wave >> 1) * 64, wn = (wave & 1) * 64;
    const int col16 = lane & 15, quad = lane >> 4;
    const float scale = 0.03125f;  // 1024^-0.5
    __half* Sb = S + (size_t)b * SEQ * SEQ;
    #pragma unroll
    for (int i = 0; i < 4; ++i)
        #pragma unroll
        for (int j = 0; j < 4; ++j) {
            const int t = jt * 128 + wn + j * 16 + col16;
            #pragma unroll
            for (int r = 0; r < 4; ++r) {
                const int s = it * 128 + wm + i * 16 + quad * 4 + r;
                Sb[(size_t)s * SEQ + t] = __float2half(acc[i][j][r] * scale);
            }
        }
}

// ---------------------------------------------------------------------------
// PV GEMM: out[{r,i}][b][s][d] fp32 = P[b] @ VTstack[b]^T, K extent causal.
// grid (16 n-tiles, 16 s-tiles, 4 batches). n<1024 -> real, else imag.
// ---------------------------------------------------------------------------
__global__ __launch_bounds__(256)
void gemm_pv(const ushort_t* __restrict__ P, const ushort_t* __restrict__ VT,
             float* __restrict__ out)
{
    const int nt = blockIdx.x, mt = blockIdx.y, b = blockIdx.z;
    __shared__ ushort_t Asm[128 * 32], Bsm[128 * 32];
    const int tid = threadIdx.x, wave = tid >> 6, lane = tid & 63;
    const int kend = (mt + 1) * 128;
    float4v acc[4][4] = {};
    gemm_core(P + (size_t)b * SEQ * SEQ + (size_t)mt * 128 * LD,
              VT + (size_t)b * LD * LD + (size_t)nt * 128 * LD,
              0, kend, Asm, Bsm, acc, wave, lane);

    const int wm = (wave >> 1) * 64, wn = (wave & 1) * 64;
    const int col16 = lane & 15, quad = lane >> 4;
    #pragma unroll
    for (int i = 0; i < 4; ++i)
        #pragma unroll
        for (int j = 0; j < 4; ++j) {
            const int n = nt * 128 + wn + j * 16 + col16;
            float* dst = out + ((n < 1024) ? 0 : PROJ_ELEMS);
            const int d = n & 1023;
            #pragma unroll
            for (int r = 0; r < 4; ++r) {
                const int s = mt * 128 + wm + i * 16 + quad * 4 + r;
                dst[((size_t)b * SEQ + s) * DIMK + d] = acc[i][j][r];
            }
        }
}

// ---------------------------------------------------------------------------
// Input converts
// ---------------------------------------------------------------------------
__global__ __launch_bounds__(256)
void zcat_kernel(const float* __restrict__ zr, const float* __restrict__ zi,
                 ushort_t* __restrict__ zcat)
{
    const size_t e = ((size_t)blockIdx.x * 256 + threadIdx.x) * 8;
    const size_t tok = e >> 11;
    const int c = (int)(e & 2047);
    const float* src = (c < 1024) ? (zr + tok * 1024 + c) : (zi + tok * 1024 + (c - 1024));
    float4 a = *(const float4*)src;
    float4 b = *(const float4*)(src + 4);
    ushort_t* d = zcat + e;
    d[0]=f2bf(a.x); d[1]=f2bf(a.y); d[2]=f2bf(a.z); d[3]=f2bf(a.w);
    d[4]=f2bf(b.x); d[5]=f2bf(b.y); d[6]=f2bf(b.z); d[7]=f2bf(b.w);
}

// Wstack[n][c]: n<1024: [wr[n] | -wi[n]] ; n>=1024: [wi[n-1024] | wr[n-1024]]
__global__ __launch_bounds__(256)
void wstack_kernel(const float* __restrict__ wr, const float* __restrict__ wi,
                   ushort_t* __restrict__ ws)
{
    const size_t e = ((size_t)blockIdx.x * 256 + threadIdx.x) * 8;
    const int n = (int)(e >> 11), c = (int)(e & 2047);
    const int n1 = n & 1023, c1 = c & 1023;
    const float* src;
    float sgn = 1.f;
    if (n < 1024) {
        if (c < 1024) src = wr + (size_t)n1 * 1024 + c1;
        else        { src = wi + (size_t)n1 * 1024 + c1; sgn = -1.f; }
    } else {
        src = ((c < 1024) ? wi : wr) + (size_t)n1 * 1024 + c1;
    }
    float4 a = *(const float4*)src;
    float4 b = *(const float4*)(src + 4);
    ushort_t* d = ws + e;
    d[0]=f2bf(sgn*a.x); d[1]=f2bf(sgn*a.y); d[2]=f2bf(sgn*a.z); d[3]=f2bf(sgn*a.w);
    d[4]=f2bf(sgn*b.x); d[5]=f2bf(sgn*b.y); d[6]=f2bf(sgn*b.z); d[7]=f2bf(sgn*b.w);
}

// ---------------------------------------------------------------------------
// V transpose per batch: VT[b][c][t] = Vcat[b*SEQ + t][c], 64x64 LDS tiles.
// grid (32 t-tiles, 32 c-tiles, 4 batches)
// ---------------------------------------------------------------------------
__global__ __launch_bounds__(256)
void transpose_v(const ushort_t* __restrict__ vcat, ushort_t* __restrict__ vt)
{
    __shared__ ushort_t tile[64][65];
    const int b = blockIdx.z;
    const int t0 = blockIdx.x * 64, c0 = blockIdx.y * 64;
    const int tid = threadIdx.x;
    const int r = tid >> 4, c4 = (tid & 15) * 4;
    const ushort_t* src = vcat + ((size_t)(b * SEQ + t0)) * LD + c0;
    #pragma unroll
    for (int p = 0; p < 4; ++p) {
        const int row = p * 16 + r;
        ushort4 v = *(const ushort4*)(src + (size_t)row * LD + c4);
        tile[row][c4+0]=v.x; tile[row][c4+1]=v.y; tile[row][c4+2]=v.z; tile[row][c4+3]=v.w;
    }
    __syncthreads();
    ushort_t* dst = vt + ((size_t)b * LD + c0) * LD + t0;
    #pragma unroll
    for (int p = 0; p < 4; ++p) {
        const int crow = p * 16 + r;
        ushort4 v;
        v.x = tile[c4+0][crow]; v.y = tile[c4+1][crow];
        v.z = tile[c4+2][crow]; v.w = tile[c4+3][crow];
        *(ushort4*)(dst + (size_t)crow * LD + c4) = v;
    }
}

// ---------------------------------------------------------------------------
// Causal softmax: read fp16 scores row [0,s], write bf16 P in place,
// zero-padded to a 128 multiple so PV consumes whole K tiles.
// ---------------------------------------------------------------------------
__global__ __launch_bounds__(256)
void softmax_kernel(__half* __restrict__ sc)
{
    const int row = blockIdx.x;          // b*SEQ + s
    const int s = row & (SEQ - 1);
    __half* x = sc + (size_t)row * SEQ;
    ushort_t* xo = (ushort_t*)x;
    const int n = s + 1;
    const int tid = threadIdx.x, wave = tid >> 6, lane = tid & 63;
    __shared__ float redm[4], reds[4];

    float m = -1e30f;
    for (int i = tid; i < n; i += 256) m = fmaxf(m, __half2float(x[i]));
    #pragma unroll
    for (int off = 32; off > 0; off >>= 1) m = fmaxf(m, __shfl_down(m, off, 64));
    if (lane == 0) redm[wave] = m;
    __syncthreads();
    if (tid == 0) redm[0] = fmaxf(fmaxf(redm[0], redm[1]), fmaxf(redm[2], redm[3]));
    __syncthreads();
    m = redm[0];

    float l = 0.f;
    for (int i = tid; i < n; i += 256) l += __expf(__half2float(x[i]) - m);
    #pragma unroll
    for (int off = 32; off > 0; off >>= 1) l += __shfl_down(l, off, 64);
    if (lane == 0) reds[wave] = l;
    __syncthreads();
    if (tid == 0) reds[0] = reds[0] + reds[1] + reds[2] + reds[3];
    __syncthreads();
    const float inv = 1.0f / reds[0];

    const int npad = min(SEQ, ((s >> 7) + 1) << 7);
    for (int i = tid; i < npad; i += 256) {
        float v = (i < n) ? __expf(__half2float(x[i]) - m) * inv : 0.f;
        xo[i] = f2bf(v);
    }
}

// ---------------------------------------------------------------------------
extern "C" void kernel_launch(void* const* d_in, const int* in_sizes, int n_in,
                              void* d_out, int out_size, void* d_ws, size_t ws_size,
                              hipStream_t stream)
{
    const float* z_real = (const float*)d_in[0];
    const float* z_imag = (const float*)d_in[1];
    const float* wq_r   = (const float*)d_in[2];
    const float* wq_i   = (const float*)d_in[3];
    const float* wk_r   = (const float*)d_in[4];
    const float* wk_i   = (const float*)d_in[5];
    const float* wv_r   = (const float*)d_in[6];
    const float* wv_i   = (const float*)d_in[7];
    // d_in[8]: causal tril mask, handled analytically.

    // Workspace layout (bytes), lifetimes are disjoint by stream order:
    //   [0,          33554432)  Zcat bf16     -> reused as VT bf16
    //   [33554432,   58720256)  Wstack q/k/v bf16 (3 x 8 MiB)
    //   [58720256,   92274688)  Qcat bf16
    //   [92274688,  125829120)  Kcat bf16
    //   [125829120, 159383552)  Vcat bf16     -> reused as scores fp16 / P bf16
    uint8_t* ws = (uint8_t*)d_ws;
    ushort_t* zcat = (ushort_t*)(ws + 0);
    ushort_t* wsq  = (ushort_t*)(ws + 33554432);
    ushort_t* wsk  = (ushort_t*)(ws + 33554432 + 8388608);
    ushort_t* wsv  = (ushort_t*)(ws + 33554432 + 16777216);
    ushort_t* qcat = (ushort_t*)(ws + 58720256);
    ushort_t* kcat = (ushort_t*)(ws + 92274688);
    ushort_t* vcat = (ushort_t*)(ws + 125829120);
    ushort_t* vt   = (ushort_t*)(ws + 0);
    __half*   sc   = (__half*)(ws + 125829120);
    float*    outp = (float*)d_out;

    zcat_kernel<<<dim3(8192), dim3(256), 0, stream>>>(z_real, z_imag, zcat);
    wstack_kernel<<<dim3(2048), dim3(256), 0, stream>>>(wq_r, wq_i, wsq);
    wstack_kernel<<<dim3(2048), dim3(256), 0, stream>>>(wk_r, wk_i, wsk);
    wstack_kernel<<<dim3(2048), dim3(256), 0, stream>>>(wv_r, wv_i, wsv);

    gemm_proj<<<dim3(16, 64), dim3(256), 0, stream>>>(zcat, wsq, qcat);
    gemm_proj<<<dim3(16, 64), dim3(256), 0, stream>>>(zcat, wsk, kcat);
    gemm_proj<<<dim3(16, 64), dim3(256), 0, stream>>>(zcat, wsv, vcat);

    transpose_v<<<dim3(32, 32, 4), dim3(256), 0, stream>>>(vcat, vt);
    gemm_scores<<<dim3(16, 16, 4), dim3(256), 0, stream>>>(qcat, kcat, sc);
    softmax_kernel<<<dim3(NTOK), dim3(256), 0, stream>>>(sc);
    gemm_pv<<<dim3(16, 16, 4), dim3(256), 0, stream>>>((ushort_t*)sc, vt, outp);
}

// Round 5
// 531.882 us; speedup vs baseline: 1.6356x; 1.1864x over previous
//
#include <hip/hip_runtime.h>
#include <hip/hip_bf16.h>
#include <hip/hip_fp16.h>

#define DIMK 1024
#define SEQ  2048
#define BATCH 4
#define NTOK (BATCH*SEQ)                    // 8192
#define PROJ_ELEMS ((size_t)NTOK*DIMK)      // 8388608
#define LD 2048                             // leading dim (elements) of every GEMM operand

typedef unsigned short ushort_t;
typedef __attribute__((ext_vector_type(8))) short short8;   // 8 x bf16 (4 VGPRs)
typedef __attribute__((ext_vector_type(4))) float float4v;  // MFMA accumulator

__device__ __forceinline__ unsigned short f2bf(float f) {
    union { float f; unsigned int i; } x; x.f = f;
    unsigned int r = x.i + 0x7fffu + ((x.i >> 16) & 1u);    // RNE
    return (unsigned short)(r >> 16);
}

// global -> LDS direct copy, 16 B per lane. LDS dest is wave-uniform base;
// HW scatters lane i to base + i*16. Source address is PER-LANE but MUST keep
// consecutive-lane groups within aligned lines for coalescing (R3 lesson).
__device__ __forceinline__ void gld_lds16(const void* g, void* l) {
    auto gp = reinterpret_cast<const __attribute__((address_space(1))) unsigned int*>(
        reinterpret_cast<uintptr_t>(g));
    auto lp = reinterpret_cast<__attribute__((address_space(3))) unsigned int*>(
        reinterpret_cast<uintptr_t>(l));
    __builtin_amdgcn_global_load_lds(gp, lp, 16, 0, 0);
}

// ---------------------------------------------------------------------------
// Shared MFMA core, BK=64: C(128x128) += A(128xK) * B(128xK)^T, row-major
// bf16, ld=2048. Block = 256 threads = 4 waves (2x2 of 64x64).
// Per barrier cycle: stage TWO 128x32 chunks of A and B (8 global_load_lds
// of 16B), one barrier, 16 ds_read_b128 + 32 MFMA per wave, barrier.
// LDS swizzle (R4, verified conflict-free + coalesced): within each 16-row
// sub-chunk, row g's 16B chunk c sits at slot (c + g/2) & 3 — a permutation
// inside each 64B line, so staging lanes 4g..4g+3 still cover one aligned
// 64B segment; fragment reads hit all 32 banks per 8 lanes.
// ---------------------------------------------------------------------------
__device__ __forceinline__ void gemm_core(
    const ushort_t* __restrict__ Arow,   // A + m0*LD
    const ushort_t* __restrict__ Brow,   // B + n0*LD
    int kbeg, int kend,                  // multiples of 64
    ushort_t* Asm, ushort_t* Bsm,        // LDS, 128*64 bf16 each (2 halves of 8 sub-chunks x 512)
    float4v acc[4][4], int wave, int lane)
{
    const int g  = lane >> 2;                         // staging row within sub-chunk
    const int sx = lane & 3;                          // staging slot within 64B line
    const int scol = (((sx - (g >> 1)) & 3)) * 8;     // swizzled source chunk (elements)
    const int sc0 = wave * 2, sc1 = wave * 2 + 1;     // this wave's staging sub-chunks
    const int r16  = lane & 15;                       // fragment row
    const int quad = lane >> 4;                       // fragment k-chunk
    const int swz  = ((quad + (r16 >> 1)) & 3) * 8;   // swizzled read chunk (elements)
    const int cA = (wave >> 1) * 4;                   // wave's A sub-chunk base
    const int cB = (wave & 1) * 4;                    // wave's B sub-chunk base

    for (int k0 = kbeg; k0 < kend; k0 += 64) {
        #pragma unroll
        for (int h = 0; h < 2; ++h) {
            const int kh = k0 + h * 32;
            ushort_t* Ah = Asm + h * 4096;
            ushort_t* Bh = Bsm + h * 4096;
            gld_lds16(Arow + (size_t)(sc0 * 16 + g) * LD + kh + scol, Ah + sc0 * 512);
            gld_lds16(Arow + (size_t)(sc1 * 16 + g) * LD + kh + scol, Ah + sc1 * 512);
            gld_lds16(Brow + (size_t)(sc0 * 16 + g) * LD + kh + scol, Bh + sc0 * 512);
            gld_lds16(Brow + (size_t)(sc1 * 16 + g) * LD + kh + scol, Bh + sc1 * 512);
        }
        __syncthreads();
        #pragma unroll
        for (int h = 0; h < 2; ++h) {
            const ushort_t* Ah = Asm + h * 4096;
            const ushort_t* Bh = Bsm + h * 4096;
            short8 af[4], bfr[4];
            #pragma unroll
            for (int i = 0; i < 4; ++i)
                af[i] = *(const short8*)(Ah + (cA + i) * 512 + r16 * 32 + swz);
            #pragma unroll
            for (int j = 0; j < 4; ++j)
                bfr[j] = *(const short8*)(Bh + (cB + j) * 512 + r16 * 32 + swz);
            #pragma unroll
            for (int i = 0; i < 4; ++i)
                #pragma unroll
                for (int j = 0; j < 4; ++j)
                    acc[i][j] = __builtin_amdgcn_mfma_f32_16x16x32_bf16(af[i], bfr[j], acc[i][j], 0, 0, 0);
        }
        __syncthreads();
    }
}

// ---------------------------------------------------------------------------
// Merged projection GEMM: [Q|K|V]cat[8192,2048] = Zcat[8192,2048] @ Wall^T,
// Wall = [Wsq;Wsk;Wsv] rows 0..6143. grid (48, 64); n-tile picks the output.
// ---------------------------------------------------------------------------
__global__ __launch_bounds__(256, 2)
void gemm_proj(const ushort_t* __restrict__ A, const ushort_t* __restrict__ B,
               ushort_t* __restrict__ Cq, ushort_t* __restrict__ Ck,
               ushort_t* __restrict__ Cv)
{
    __shared__ ushort_t Asm[128 * 64], Bsm[128 * 64];
    const int tid = threadIdx.x, wave = tid >> 6, lane = tid & 63;
    const int m0 = blockIdx.y * 128;
    const int n0g = blockIdx.x * 128;               // 0..6143
    ushort_t* C = (n0g < 2048) ? Cq : ((n0g < 4096) ? Ck : Cv);
    const int n0 = n0g & 2047;
    float4v acc[4][4] = {};
    gemm_core(A + (size_t)m0 * LD, B + (size_t)n0g * LD, 0, 2048, Asm, Bsm, acc, wave, lane);

    const int wm = (wave >> 1) * 64, wn = (wave & 1) * 64;
    const int col16 = lane & 15, quad = lane >> 4;
    #pragma unroll
    for (int i = 0; i < 4; ++i)
        #pragma unroll
        for (int j = 0; j < 4; ++j) {
            const int n = n0 + wn + j * 16 + col16;
            #pragma unroll
            for (int r = 0; r < 4; ++r) {
                const int m = m0 + wm + i * 16 + quad * 4 + r;
                C[(size_t)m * LD + n] = f2bf(acc[i][j][r]);
            }
        }
}

// ---------------------------------------------------------------------------
// Scores GEMM (causal tiles): S[b][s][t] fp16 = (Qcat@Kcat^T)*scale
// grid (16 t-tiles, 16 s-tiles, 4 batches); skip jt>it.
// ---------------------------------------------------------------------------
__global__ __launch_bounds__(256, 2)
void gemm_scores(const ushort_t* __restrict__ Q, const ushort_t* __restrict__ K,
                 __half* __restrict__ S)
{
    const int jt = blockIdx.x, it = blockIdx.y, b = blockIdx.z;
    if (jt > it) return;
    __shared__ ushort_t Asm[128 * 64], Bsm[128 * 64];
    const int tid = threadIdx.x, wave = tid >> 6, lane = tid & 63;
    const size_t boff = (size_t)b * SEQ * LD;
    float4v acc[4][4] = {};
    gemm_core(Q + boff + (size_t)it * 128 * LD, K + boff + (size_t)jt * 128 * LD,
              0, 2048, Asm, Bsm, acc, wave, lane);

    const int wm = (wave >> 1) * 64, wn = (wave & 1) * 64;
    const int col16 = lane & 15, quad = lane >> 4;
    const float scale = 0.03125f;  // 1024^-0.5
    __half* Sb = S + (size_t)b * SEQ * SEQ;
    #pragma unroll
    for (int i = 0; i < 4; ++i)
        #pragma unroll
        for (int j = 0; j < 4; ++j) {
            const int t = jt * 128 + wn + j * 16 + col16;
            #pragma unroll
            for (int r = 0; r < 4; ++r) {
                const int s = it * 128 + wm + i * 16 + quad * 4 + r;
                Sb[(size_t)s * SEQ + t] = __float2half(acc[i][j][r] * scale);
            }
        }
}

// ---------------------------------------------------------------------------
// PV GEMM: out[{r,i}][b][s][d] fp32 = P[b] @ VTstack[b]^T, K extent causal.
// grid (16 n-tiles, 16 s-tiles, 4 batches). n<1024 -> real, else imag.
// ---------------------------------------------------------------------------
__global__ __launch_bounds__(256, 2)
void gemm_pv(const ushort_t* __restrict__ P, const ushort_t* __restrict__ VT,
             float* __restrict__ out)
{
    const int nt = blockIdx.x, mt = blockIdx.y, b = blockIdx.z;
    __shared__ ushort_t Asm[128 * 64], Bsm[128 * 64];
    const int tid = threadIdx.x, wave = tid >> 6, lane = tid & 63;
    const int kend = (mt + 1) * 128;
    float4v acc[4][4] = {};
    gemm_core(P + (size_t)b * SEQ * SEQ + (size_t)mt * 128 * LD,
              VT + (size_t)b * LD * LD + (size_t)nt * 128 * LD,
              0, kend, Asm, Bsm, acc, wave, lane);

    const int wm = (wave >> 1) * 64, wn = (wave & 1) * 64;
    const int col16 = lane & 15, quad = lane >> 4;
    #pragma unroll
    for (int i = 0; i < 4; ++i)
        #pragma unroll
        for (int j = 0; j < 4; ++j) {
            const int n = nt * 128 + wn + j * 16 + col16;
            float* dst = out + ((n < 1024) ? 0 : PROJ_ELEMS);
            const int d = n & 1023;
            #pragma unroll
            for (int r = 0; r < 4; ++r) {
                const int s = mt * 128 + wm + i * 16 + quad * 4 + r;
                dst[((size_t)b * SEQ + s) * DIMK + d] = acc[i][j][r];
            }
        }
}

// ---------------------------------------------------------------------------
// Input converts
// ---------------------------------------------------------------------------
__global__ __launch_bounds__(256)
void zcat_kernel(const float* __restrict__ zr, const float* __restrict__ zi,
                 ushort_t* __restrict__ zcat)
{
    const size_t e = ((size_t)blockIdx.x * 256 + threadIdx.x) * 8;
    const size_t tok = e >> 11;
    const int c = (int)(e & 2047);
    const float* src = (c < 1024) ? (zr + tok * 1024 + c) : (zi + tok * 1024 + (c - 1024));
    float4 a = *(const float4*)src;
    float4 b = *(const float4*)(src + 4);
    ushort_t* d = zcat + e;
    d[0]=f2bf(a.x); d[1]=f2bf(a.y); d[2]=f2bf(a.z); d[3]=f2bf(a.w);
    d[4]=f2bf(b.x); d[5]=f2bf(b.y); d[6]=f2bf(b.z); d[7]=f2bf(b.w);
}

// Wstack[n][c]: n<1024: [wr[n] | -wi[n]] ; n>=1024: [wi[n-1024] | wr[n-1024]]
__global__ __launch_bounds__(256)
void wstack_kernel(const float* __restrict__ wr, const float* __restrict__ wi,
                   ushort_t* __restrict__ ws)
{
    const size_t e = ((size_t)blockIdx.x * 256 + threadIdx.x) * 8;
    const int n = (int)(e >> 11), c = (int)(e & 2047);
    const int n1 = n & 1023, c1 = c & 1023;
    const float* src;
    float sgn = 1.f;
    if (n < 1024) {
        if (c < 1024) src = wr + (size_t)n1 * 1024 + c1;
        else        { src = wi + (size_t)n1 * 1024 + c1; sgn = -1.f; }
    } else {
        src = ((c < 1024) ? wi : wr) + (size_t)n1 * 1024 + c1;
    }
    float4 a = *(const float4*)src;
    float4 b = *(const float4*)(src + 4);
    ushort_t* d = ws + e;
    d[0]=f2bf(sgn*a.x); d[1]=f2bf(sgn*a.y); d[2]=f2bf(sgn*a.z); d[3]=f2bf(sgn*a.w);
    d[4]=f2bf(sgn*b.x); d[5]=f2bf(sgn*b.y); d[6]=f2bf(sgn*b.z); d[7]=f2bf(sgn*b.w);
}

// ---------------------------------------------------------------------------
// V transpose per batch: VT[b][c][t] = Vcat[b*SEQ + t][c], 64x64 LDS tiles.
// grid (32 t-tiles, 32 c-tiles, 4 batches)
// ---------------------------------------------------------------------------
__global__ __launch_bounds__(256)
void transpose_v(const ushort_t* __restrict__ vcat, ushort_t* __restrict__ vt)
{
    __shared__ ushort_t tile[64][65];
    const int b = blockIdx.z;
    const int t0 = blockIdx.x * 64, c0 = blockIdx.y * 64;
    const int tid = threadIdx.x;
    const int r = tid >> 4, c4 = (tid & 15) * 4;
    const ushort_t* src = vcat + ((size_t)(b * SEQ + t0)) * LD + c0;
    #pragma unroll
    for (int p = 0; p < 4; ++p) {
        const int row = p * 16 + r;
        ushort4 v = *(const ushort4*)(src + (size_t)row * LD + c4);
        tile[row][c4+0]=v.x; tile[row][c4+1]=v.y; tile[row][c4+2]=v.z; tile[row][c4+3]=v.w;
    }
    __syncthreads();
    ushort_t* dst = vt + ((size_t)b * LD + c0) * LD + t0;
    #pragma unroll
    for (int p = 0; p < 4; ++p) {
        const int crow = p * 16 + r;
        ushort4 v;
        v.x = tile[c4+0][crow]; v.y = tile[c4+1][crow];
        v.z = tile[c4+2][crow]; v.w = tile[c4+3][crow];
        *(ushort4*)(dst + (size_t)crow * LD + c4) = v;
    }
}

// ---------------------------------------------------------------------------
// Causal softmax: read fp16 scores row [0,s], write bf16 P in place,
// zero-padded to a 128 multiple so PV consumes whole K tiles.
// ---------------------------------------------------------------------------
__global__ __launch_bounds__(256)
void softmax_kernel(__half* __restrict__ sc)
{
    const int row = blockIdx.x;          // b*SEQ + s
    const int s = row & (SEQ - 1);
    __half* x = sc + (size_t)row * SEQ;
    ushort_t* xo = (ushort_t*)x;
    const int n = s + 1;
    const int tid = threadIdx.x, wave = tid >> 6, lane = tid & 63;
    __shared__ float redm[4], reds[4];

    float m = -1e30f;
    for (int i = tid; i < n; i += 256) m = fmaxf(m, __half2float(x[i]));
    #pragma unroll
    for (int off = 32; off > 0; off >>= 1) m = fmaxf(m, __shfl_down(m, off, 64));
    if (lane == 0) redm[wave] = m;
    __syncthreads();
    if (tid == 0) redm[0] = fmaxf(fmaxf(redm[0], redm[1]), fmaxf(redm[2], redm[3]));
    __syncthreads();
    m = redm[0];

    float l = 0.f;
    for (int i = tid; i < n; i += 256) l += __expf(__half2float(x[i]) - m);
    #pragma unroll
    for (int off = 32; off > 0; off >>= 1) l += __shfl_down(l, off, 64);
    if (lane == 0) reds[wave] = l;
    __syncthreads();
    if (tid == 0) reds[0] = reds[0] + reds[1] + reds[2] + reds[3];
    __syncthreads();
    const float inv = 1.0f / reds[0];

    const int npad = min(SEQ, ((s >> 7) + 1) << 7);
    for (int i = tid; i < npad; i += 256) {
        float v = (i < n) ? __expf(__half2float(x[i]) - m) * inv : 0.f;
        xo[i] = f2bf(v);
    }
}

// ---------------------------------------------------------------------------
extern "C" void kernel_launch(void* const* d_in, const int* in_sizes, int n_in,
                              void* d_out, int out_size, void* d_ws, size_t ws_size,
                              hipStream_t stream)
{
    const float* z_real = (const float*)d_in[0];
    const float* z_imag = (const float*)d_in[1];
    const float* wq_r   = (const float*)d_in[2];
    const float* wq_i   = (const float*)d_in[3];
    const float* wk_r   = (const float*)d_in[4];
    const float* wk_i   = (const float*)d_in[5];
    const float* wv_r   = (const float*)d_in[6];
    const float* wv_i   = (const float*)d_in[7];
    // d_in[8]: causal tril mask, handled analytically.

    // Workspace layout (bytes), lifetimes are disjoint by stream order:
    //   [0,          33554432)  Zcat bf16     -> reused as VT bf16
    //   [33554432,   58720256)  Wstack q/k/v bf16 (3 x 8 MiB, contiguous = Wall[6144,2048])
    //   [58720256,   92274688)  Qcat bf16
    //   [92274688,  125829120)  Kcat bf16
    //   [125829120, 159383552)  Vcat bf16     -> reused as scores fp16 / P bf16
    uint8_t* ws = (uint8_t*)d_ws;
    ushort_t* zcat = (ushort_t*)(ws + 0);
    ushort_t* wall = (ushort_t*)(ws + 33554432);
    ushort_t* wsq  = wall;
    ushort_t* wsk  = (ushort_t*)(ws + 33554432 + 8388608);
    ushort_t* wsv  = (ushort_t*)(ws + 33554432 + 16777216);
    ushort_t* qcat = (ushort_t*)(ws + 58720256);
    ushort_t* kcat = (ushort_t*)(ws + 92274688);
    ushort_t* vcat = (ushort_t*)(ws + 125829120);
    ushort_t* vt   = (ushort_t*)(ws + 0);
    __half*   sc   = (__half*)(ws + 125829120);
    float*    outp = (float*)d_out;

    zcat_kernel<<<dim3(8192), dim3(256), 0, stream>>>(z_real, z_imag, zcat);
    wstack_kernel<<<dim3(2048), dim3(256), 0, stream>>>(wq_r, wq_i, wsq);
    wstack_kernel<<<dim3(2048), dim3(256), 0, stream>>>(wk_r, wk_i, wsk);
    wstack_kernel<<<dim3(2048), dim3(256), 0, stream>>>(wv_r, wv_i, wsv);

    gemm_proj<<<dim3(48, 64), dim3(256), 0, stream>>>(zcat, wall, qcat, kcat, vcat);

    transpose_v<<<dim3(32, 32, 4), dim3(256), 0, stream>>>(vcat, vt);
    gemm_scores<<<dim3(16, 16, 4), dim3(256), 0, stream>>>(qcat, kcat, sc);
    softmax_kernel<<<dim3(NTOK), dim3(256), 0, stream>>>(sc);
    gemm_pv<<<dim3(16, 16, 4), dim3(256), 0, stream>>>((ushort_t*)sc, vt, outp);
}